// Round 1
// baseline (198.833 us; speedup 1.0000x reference)
//
#include <hip/hip_runtime.h>
#include <hip/hip_bf16.h>

using f32x4  = __attribute__((ext_vector_type(4))) float;
using bf16x8 = __attribute__((ext_vector_type(8))) short;
typedef unsigned int u32;

__device__ __forceinline__ unsigned short f2bf(float f) {
  u32 u = __float_as_uint(f);
  u += 0x7FFFu + ((u >> 16) & 1u);          // round-to-nearest-even
  return (unsigned short)(u >> 16);
}

__global__ __launch_bounds__(256) void laa_fused(
    const float* __restrict__ x, const void* __restrict__ maskp,
    const float* __restrict__ Wq, const float* __restrict__ bq,
    const float* __restrict__ Wk, const float* __restrict__ bk,
    const float* __restrict__ Wv, const float* __restrict__ bv,
    const float* __restrict__ Wo, const float* __restrict__ bo,
    float* __restrict__ out, int n_tiles)
{
  constexpr int C = 128;
  __shared__ __align__(128) unsigned short Qlds[16 * 128];
  __shared__ __align__(128) unsigned short Klds[16 * 128];
  __shared__ __align__(128) unsigned short VTlds[128 * 24]; // [ch][row], stride 24 shorts
  __shared__ __align__(128) unsigned short Olds[16 * 128];

  const int tid  = threadIdx.x;
  const int wave = tid >> 6;
  const int lane = tid & 63;
  const int c0   = lane & 15;
  const int g    = lane >> 4;

  // ---- mask dtype detection (int32 upload -> upper bytes all zero) ----
  const u32* mw = (const u32*)maskp;
  u32 det = 0;
  #pragma unroll
  for (int i = 0; i < 64; ++i) det |= mw[i];
  const bool mask_is_byte = (det & 0xFFFFFF00u) != 0u;

  // ---- per-wave weight B-fragments in registers (ch slice 32*wave..+31) ----
  bf16x8 wqf[2][4], wkf[2][4], wvf[2][4], wof[2][4];
  float bq2[2], bk2[2], bv2[2], bo2[2];
  #pragma unroll
  for (int t = 0; t < 2; ++t) {
    const int col = 16 * (2 * wave + t) + c0;
    bq2[t] = bq[col]; bk2[t] = bk[col]; bv2[t] = bv[col]; bo2[t] = bo[col];
    #pragma unroll
    for (int kk = 0; kk < 4; ++kk) {
      const int kb = 32 * kk + 8 * g;
      bf16x8 aq, ak, av, ao;
      #pragma unroll
      for (int j = 0; j < 8; ++j) {
        const int idx = (kb + j) * C + col;
        aq[j] = (short)f2bf(Wq[idx]);
        ak[j] = (short)f2bf(Wk[idx]);
        av[j] = (short)f2bf(Wv[idx]);
        ao[j] = (short)f2bf(Wo[idx]);
      }
      wqf[t][kk] = aq; wkf[t][kk] = ak; wvf[t][kk] = av; wof[t][kk] = ao;
    }
  }

  const float scale = 0.17677669529663687f; // 1/sqrt(32)

  for (int tile = blockIdx.x; tile < n_tiles; tile += gridDim.x) {
    const int rowbase = tile * 16;
    const float* xt = x + (size_t)rowbase * C;

    // ---- x A-fragments straight from global ----
    bf16x8 af[4];
    #pragma unroll
    for (int kk = 0; kk < 4; ++kk) {
      const float4* p = reinterpret_cast<const float4*>(xt + c0 * C + 32 * kk + 8 * g);
      float4 u0 = p[0], u1 = p[1];
      bf16x8 a;
      a[0]=(short)f2bf(u0.x); a[1]=(short)f2bf(u0.y); a[2]=(short)f2bf(u0.z); a[3]=(short)f2bf(u0.w);
      a[4]=(short)f2bf(u1.x); a[5]=(short)f2bf(u1.y); a[6]=(short)f2bf(u1.z); a[7]=(short)f2bf(u1.w);
      af[kk] = a;
    }

    // ---- key mask for residue g of this tile (rows 4g..4g+3) ----
    float kvf[4];
    #pragma unroll
    for (int i = 0; i < 4; ++i) {
      const int idx = rowbase + 4 * g + i;
      const int mv = mask_is_byte ? (int)((const unsigned char*)maskp)[idx]
                                  : ((const int*)maskp)[idx];
      kvf[i] = (mv != 0) ? 1.0f : 0.0f;
    }

    // ---- QKV projections (bias preloaded into acc) ----
    f32x4 qa[2], ka[2], va[2];
    #pragma unroll
    for (int t = 0; t < 2; ++t) {
      qa[t] = f32x4{bq2[t], bq2[t], bq2[t], bq2[t]};
      ka[t] = f32x4{bk2[t], bk2[t], bk2[t], bk2[t]};
      va[t] = f32x4{bv2[t], bv2[t], bv2[t], bv2[t]};
    }
    #pragma unroll
    for (int kk = 0; kk < 4; ++kk) {
      #pragma unroll
      for (int t = 0; t < 2; ++t) {
        qa[t] = __builtin_amdgcn_mfma_f32_16x16x32_bf16(af[kk], wqf[t][kk], qa[t], 0, 0, 0);
        ka[t] = __builtin_amdgcn_mfma_f32_16x16x32_bf16(af[kk], wkf[t][kk], ka[t], 0, 0, 0);
        va[t] = __builtin_amdgcn_mfma_f32_16x16x32_bf16(af[kk], wvf[t][kk], va[t], 0, 0, 0);
      }
    }

    // ---- stage Q,K (swizzled) and V^T  (wave-private LDS slices) ----
    #pragma unroll
    for (int t = 0; t < 2; ++t) {
      const int ch = 16 * (2 * wave + t) + c0;
      #pragma unroll
      for (int i = 0; i < 4; ++i) {
        const int row = 4 * g + i;
        const int off = (row * 256 + ch * 2) ^ ((row & 7) << 4);
        *(unsigned short*)((char*)Qlds + off) = f2bf(qa[t][i] * scale);
        *(unsigned short*)((char*)Klds + off) = f2bf(ka[t][i]);
        VTlds[ch * 24 + row] = f2bf(va[t][i]);
      }
    }

    // ---- S^T = K_h * Q_h^T  (head h = wave): lane holds keys 4g..4g+3 of query c0 ----
    const int hch = 32 * wave;
    bf16x8 kfrag, qfrag;
    {
      const int row = c0;
      const int chb = hch + 8 * g;
      const int off = (row * 256 + chb * 2) ^ ((row & 7) << 4);
      kfrag = *(const bf16x8*)((const char*)Klds + off);
      qfrag = *(const bf16x8*)((const char*)Qlds + off);
    }
    f32x4 stv = f32x4{0.f, 0.f, 0.f, 0.f};
    stv = __builtin_amdgcn_mfma_f32_16x16x32_bf16(kfrag, qfrag, stv, 0, 0, 0);

    // ---- in-lane masked softmax over the 4 keys ----
    float mx = -1e30f;
    #pragma unroll
    for (int i = 0; i < 4; ++i) if (kvf[i] > 0.f) mx = fmaxf(mx, stv[i]);
    float p[4]; float den = 0.f;
    #pragma unroll
    for (int i = 0; i < 4; ++i) {
      p[i] = (kvf[i] > 0.f && mx > -1e29f) ? __expf(stv[i] - mx) : 0.f;
      den += p[i];
    }
    const float inv = den > 0.f ? 1.0f / den : 0.f;
    const bool diag = ((c0 >> 2) == g);
    u32 p01 = 0u, p23 = 0u;
    if (diag) {
      p01 = (u32)f2bf(p[0] * inv) | ((u32)f2bf(p[1] * inv) << 16);
      p23 = (u32)f2bf(p[2] * inv) | ((u32)f2bf(p[3] * inv) << 16);
    }

    // ---- assemble P A-fragment (query rows x 16 keys, zero-padded K=32) ----
    const int srcA = ((2 * g) * 16 + c0) * 4;
    const int srcB = ((2 * g + 1) * 16 + c0) * 4;
    u32 w0 = (u32)__builtin_amdgcn_ds_bpermute(srcA, (int)p01);
    u32 w1 = (u32)__builtin_amdgcn_ds_bpermute(srcA, (int)p23);
    u32 w2 = (u32)__builtin_amdgcn_ds_bpermute(srcB, (int)p01);
    u32 w3 = (u32)__builtin_amdgcn_ds_bpermute(srcB, (int)p23);
    if (g >= 2) { w0 = 0u; w1 = 0u; w2 = 0u; w3 = 0u; }
    bf16x8 pfrag;
    pfrag[0] = (short)(w0 & 0xFFFFu); pfrag[1] = (short)(w0 >> 16);
    pfrag[2] = (short)(w1 & 0xFFFFu); pfrag[3] = (short)(w1 >> 16);
    pfrag[4] = (short)(w2 & 0xFFFFu); pfrag[5] = (short)(w2 >> 16);
    pfrag[6] = (short)(w3 & 0xFFFFu); pfrag[7] = (short)(w3 >> 16);

    // ---- PV ----
    f32x4 oa[2];
    oa[0] = f32x4{0.f,0.f,0.f,0.f}; oa[1] = f32x4{0.f,0.f,0.f,0.f};
    #pragma unroll
    for (int nt2 = 0; nt2 < 2; ++nt2) {
      bf16x8 vfrag;
      if (g < 2) {
        const int ch = hch + 16 * nt2 + c0;
        vfrag = *(const bf16x8*)(&VTlds[ch * 24 + 8 * g]);
      } else {
        vfrag[0]=0; vfrag[1]=0; vfrag[2]=0; vfrag[3]=0;
        vfrag[4]=0; vfrag[5]=0; vfrag[6]=0; vfrag[7]=0;
      }
      oa[nt2] = __builtin_amdgcn_mfma_f32_16x16x32_bf16(pfrag, vfrag, oa[nt2], 0, 0, 0);
    }

    // ---- stage O (crosses waves) ----
    #pragma unroll
    for (int nt2 = 0; nt2 < 2; ++nt2) {
      const int ch = hch + 16 * nt2 + c0;
      #pragma unroll
      for (int i = 0; i < 4; ++i) {
        const int row = 4 * g + i;
        const int off = (row * 256 + ch * 2) ^ ((row & 7) << 4);
        *(unsigned short*)((char*)Olds + off) = f2bf(oa[nt2][i]);
      }
    }
    __syncthreads();

    // ---- final projection O @ Wo + bo ----
    bf16x8 of[4];
    #pragma unroll
    for (int kk = 0; kk < 4; ++kk) {
      const int row = c0;
      const int chb = 32 * kk + 8 * g;
      const int off = (row * 256 + chb * 2) ^ ((row & 7) << 4);
      of[kk] = *(const bf16x8*)((const char*)Olds + off);
    }
    f32x4 fa[2];
    #pragma unroll
    for (int t = 0; t < 2; ++t) fa[t] = f32x4{bo2[t], bo2[t], bo2[t], bo2[t]};
    #pragma unroll
    for (int kk = 0; kk < 4; ++kk) {
      #pragma unroll
      for (int t = 0; t < 2; ++t)
        fa[t] = __builtin_amdgcn_mfma_f32_16x16x32_bf16(of[kk], wof[t][kk], fa[t], 0, 0, 0);
    }

    // ---- store (zero fully-masked residues) ----
    const float rv = (kvf[0] + kvf[1] + kvf[2] + kvf[3]) > 0.f ? 1.0f : 0.f;
    #pragma unroll
    for (int t = 0; t < 2; ++t) {
      const int ch = 16 * (2 * wave + t) + c0;
      #pragma unroll
      for (int i = 0; i < 4; ++i) {
        const int row = rowbase + 4 * g + i;
        out[(size_t)row * C + ch] = fa[t][i] * rv;
      }
    }
    __syncthreads();
  }
}

extern "C" void kernel_launch(void* const* d_in, const int* in_sizes, int n_in,
                              void* d_out, int out_size, void* d_ws, size_t ws_size,
                              hipStream_t stream) {
  (void)n_in; (void)d_ws; (void)ws_size; (void)out_size;
  const float* x  = (const float*)d_in[0];
  const void* mask = d_in[1];
  const float* Wq = (const float*)d_in[2];
  const float* bq = (const float*)d_in[3];
  const float* Wk = (const float*)d_in[4];
  const float* bk = (const float*)d_in[5];
  const float* Wv = (const float*)d_in[6];
  const float* bv = (const float*)d_in[7];
  const float* Wo = (const float*)d_in[8];
  const float* bo = (const float*)d_in[9];
  float* out = (float*)d_out;

  const int rows = in_sizes[0] / 128;   // B*L*A
  const int n_tiles = rows / 16;
  dim3 grid(n_tiles < 512 ? n_tiles : 512), block(256);
  hipLaunchKernelGGL(laa_fused, grid, block, 0, stream,
                     x, mask, Wq, bq, Wk, bk, Wv, bv, Wo, bo, out, n_tiles);
}